// Round 3
// baseline (273.836 us; speedup 1.0000x reference)
//
#include <hip/hip_runtime.h>

typedef unsigned long long u64;

#define N_ANCHORS 4000000
#define NPAIR4    2000000      // float4 count in score (N*2/4)
#define M_TOP     2000
#define NBINS     1024
#define CAP       8192
#define NMS_THR_F 0.7f
#define SCORE_THR_F 0.5f

// workspace layout (bytes)
#define OFF_HIST   0            // 1024 u32  = 4096
#define OFF_META   4096         // 16 u32    = 64   (meta[0]=counter, meta[1]=T)
#define OFF_KEYS   4352         // 8192 u64  = 65536
#define OFF_SORTED 69888        // 2000 u64  = 16000
#define OFF_BOXES  85888        // 2000 f4   = 32000
#define OFF_FLAGS  117888       // 2000 u32  = 8000
#define OFF_MASK   131072       // 2000*32 u64 = 512000  (end 643072)
#define ZERO_BYTES 85888        // hist + meta + keys + sorted

// ---------------- pass 1: histogram of score[:,1] bits ----------------
__global__ void hist_kernel(const float4* __restrict__ s4, unsigned int* __restrict__ hist) {
  __shared__ unsigned int h[NBINS];
  for (int i = threadIdx.x; i < NBINS; i += blockDim.x) h[i] = 0;
  __syncthreads();
  int nt = gridDim.x * blockDim.x;
  for (int i = blockIdx.x * blockDim.x + threadIdx.x; i < NPAIR4; i += nt) {
    float4 v = s4[i];
    if (v.y > SCORE_THR_F) {
      unsigned b = (__float_as_uint(v.y) - 0x3F000000u) >> 13;
      atomicAdd(&h[b > 1023u ? 1023u : b], 1u);
    }
    if (v.w > SCORE_THR_F) {
      unsigned b = (__float_as_uint(v.w) - 0x3F000000u) >> 13;
      atomicAdd(&h[b > 1023u ? 1023u : b], 1u);
    }
  }
  __syncthreads();
  for (int i = threadIdx.x; i < NBINS; i += blockDim.x)
    if (h[i]) atomicAdd(&hist[i], h[i]);
}

// ---------------- find bit-threshold T so that count(bits>=T) >= M ----------------
__global__ void thresh_kernel(const unsigned int* __restrict__ hist, unsigned int* __restrict__ meta) {
  if (threadIdx.x == 0) {
    unsigned s = 0; int bstar = 0;
    for (int b = NBINS - 1; b >= 0; --b) {
      s += hist[b];
      if (s >= M_TOP) { bstar = b; break; }
    }
    meta[1] = 0x3F000000u + ((unsigned)bstar << 13);
  }
}

// ---------------- pass 2: compact candidate keys ----------------
__global__ void compact_kernel(const float4* __restrict__ s4, unsigned int* __restrict__ meta,
                               u64* __restrict__ keys) {
  unsigned T = meta[1];
  int nt = gridDim.x * blockDim.x;
  for (int i = blockIdx.x * blockDim.x + threadIdx.x; i < NPAIR4; i += nt) {
    float4 v = s4[i];
    unsigned by = __float_as_uint(v.y), bw = __float_as_uint(v.w);
    if (v.y > SCORE_THR_F && by >= T) {
      unsigned pos = atomicAdd(&meta[0], 1u);
      if (pos < CAP)
        keys[pos] = ((u64)by << 32) | (u64)(0xFFFFFFFFu - (unsigned)(2 * i));
    }
    if (v.w > SCORE_THR_F && bw >= T) {
      unsigned pos = atomicAdd(&meta[0], 1u);
      if (pos < CAP)
        keys[pos] = ((u64)bw << 32) | (u64)(0xFFFFFFFFu - (unsigned)(2 * i + 1));
    }
  }
}

// ---------------- rank-based top-M selection (replaces bitonic sort) ----------------
// rank(me) = #{keys strictly greater}; keys unique (index embedded) -> total order.
// sorted[] pre-zeroed by memset; rank < M_TOP scatters key there.
__global__ __launch_bounds__(256) void rank_kernel(const u64* __restrict__ keys,
                                                   const unsigned int* __restrict__ meta,
                                                   u64* __restrict__ sorted) {
  __shared__ u64 K[CAP];   // 64 KB
  unsigned cnt = meta[0];
  if (cnt > CAP) cnt = CAP;
  for (int i = threadIdx.x; i < CAP; i += 256)
    K[i] = (i < (int)cnt) ? keys[i] : 0ull;
  __syncthreads();
  int i = blockIdx.x * 256 + threadIdx.x;
  if (i >= (int)cnt) return;
  u64 me = K[i];
  int cnt4 = ((int)cnt + 3) & ~3;
  int r = 0;
  for (int j = 0; j < cnt4; j += 4) {
    ulonglong2 a = *(ulonglong2*)&K[j];
    ulonglong2 b = *(ulonglong2*)&K[j + 2];
    r += (int)(a.x > me) + (int)(a.y > me) + (int)(b.x > me) + (int)(b.y > me);
  }
  if (r < M_TOP) sorted[r] = me;
}

// ---------------- decode + clip + keep0 flags (strict IEEE fp32, numpy op order) ----------------
__global__ void decode_kernel(const u64* __restrict__ sorted,
                              const float4* __restrict__ anchors,
                              const float4* __restrict__ deltas,
                              float4* __restrict__ boxes,
                              unsigned int* __restrict__ flags) {
  int i = blockIdx.x * blockDim.x + threadIdx.x;
  if (i >= M_TOP) return;
  u64 key = sorted[i];
  float4 outb = make_float4(0.f, 0.f, 0.f, 0.f);
  unsigned keep0 = 0;
  if (key != 0ull) {   // real candidate (valid == true)
    unsigned idx = 0xFFFFFFFFu - (unsigned)(key & 0xFFFFFFFFull);
    float4 a = anchors[idx];
    float4 d = deltas[idx];
    float w  = __fsub_rn(a.z, a.x);
    float h  = __fsub_rn(a.w, a.y);
    float cx = __fadd_rn(a.x, __fmul_rn(0.5f, w));
    float cy = __fadd_rn(a.y, __fmul_rn(0.5f, h));
    float ncx = __fadd_rn(cx, __fmul_rn(d.x, w));
    float ncy = __fadd_rn(cy, __fmul_rn(d.y, h));
    float e2 = (float)exp((double)d.z);   // ~correctly-rounded fp32 exp
    float e3 = (float)exp((double)d.w);
    float nw = __fmul_rn(w, e2);
    float nh = __fmul_rn(h, e3);
    float hx = __fmul_rn(0.5f, nw);
    float hy = __fmul_rn(0.5f, nh);
    float x1 = __fsub_rn(ncx, hx), y1 = __fsub_rn(ncy, hy);
    float x2 = __fadd_rn(ncx, hx), y2 = __fadd_rn(ncy, hy);
    x1 = fminf(fmaxf(x1, 0.f), 1024.f);
    y1 = fminf(fmaxf(y1, 0.f), 1024.f);
    x2 = fminf(fmaxf(x2, 0.f), 1024.f);
    y2 = fminf(fmaxf(y2, 0.f), 1024.f);
    bool big = (__fsub_rn(x2, x1) >= 1.0f) && (__fsub_rn(y2, y1) >= 1.0f);
    keep0 = big ? 1u : 0u;
    outb = make_float4(x1, y1, x2, y2);
  }
  boxes[i] = outb;
  flags[i] = keep0;
}

// ---------------- suppression bitmask: mask[row][w] bit l = iou(row, w*64+l)>thr & col>row ----------------
__global__ __launch_bounds__(256) void mask_kernel(const float4* __restrict__ boxes,
                                                   u64* __restrict__ mask) {
  int row  = blockIdx.x;         // 2000 blocks
  int wv   = threadIdx.x >> 6;   // wave 0..3
  int lane = threadIdx.x & 63;
  float4 bi = boxes[row];
  float ai = __fmul_rn(__fsub_rn(bi.z, bi.x), __fsub_rn(bi.w, bi.y));
  for (int word = wv; word < 32; word += 4) {
    int col = word * 64 + lane;
    float4 bj = boxes[col < M_TOP ? col : 0];
    float aj = __fmul_rn(__fsub_rn(bj.z, bj.x), __fsub_rn(bj.w, bj.y));
    float ltx = fmaxf(bi.x, bj.x), lty = fmaxf(bi.y, bj.y);
    float rbx = fminf(bi.z, bj.z), rby = fminf(bi.w, bj.w);
    float wx = fmaxf(__fsub_rn(rbx, ltx), 0.f);
    float wy = fmaxf(__fsub_rn(rby, lty), 0.f);
    float inter = __fmul_rn(wx, wy);
    float den = __fadd_rn(__fsub_rn(__fadd_rn(ai, aj), inter), 1e-9f);
    float iou = __fdiv_rn(inter, den);
    bool pred = (col > row) && (col < M_TOP) && (iou > NMS_THR_F);
    u64 bal = __ballot(pred);
    if (lane == 0) mask[(size_t)row * 32 + word] = bal;
  }
}

// ---------------- serial greedy NMS reduce + output write (1 wave) ----------------
// Serial chain lives in SGPRs: cur/kept scalar; readlane (no LDS) broadcasts diag words.
__global__ __launch_bounds__(64) void reduce_kernel(const u64* __restrict__ mask,
                                                    const unsigned int* __restrict__ flags,
                                                    const float4* __restrict__ boxes,
                                                    float* __restrict__ out) {
  int lane = threadIdx.x;
  int half = lane >> 5;
  int myw  = lane & 31;
  u64 k0 = 0, rem = 0;
  // pack keep0 flags into 32 words (lane w holds word w)
  for (int w = 0; w < 32; ++w) {
    int i = w * 64 + lane;
    unsigned f = (i < M_TOP) ? flags[i] : 0u;
    u64 bal = __ballot(f != 0u);
    if (lane == w) k0 = bal;
  }
  #pragma unroll
  for (int c = 0; c < 32; ++c) {
    const u64* rowbase = mask + (size_t)(c * 64) * 32;
    // vector preload: diag word for row 'lane' of chunk; my word for 32 rows of my half
    int rd = c * 64 + lane;
    u64 diag = rowbase[(size_t)(rd < M_TOP ? lane : 0) * 32 + c];
    u64 mw[32];
    #pragma unroll
    for (int b = 0; b < 32; ++b) {
      int r = half * 32 + b;
      int rr = (c * 64 + r < M_TOP) ? r : 0;
      mw[b] = rowbase[(size_t)rr * 32 + myw];
    }
    u64 alive = k0 & ~rem;
    unsigned clo = (unsigned)__builtin_amdgcn_readlane((int)(unsigned)(alive & 0xFFFFFFFFull), c);
    unsigned chi = (unsigned)__builtin_amdgcn_readlane((int)(unsigned)(alive >> 32), c);
    u64 cur = ((u64)chi << 32) | (u64)clo;    // scalar (uniform)
    u64 kept = 0;                              // scalar mask of bits kept this chunk
    #pragma unroll
    for (int b = 0; b < 64; ++b) {
      unsigned dlo = (unsigned)__builtin_amdgcn_readlane((int)(unsigned)(diag & 0xFFFFFFFFull), b);
      unsigned dhi = (unsigned)__builtin_amdgcn_readlane((int)(unsigned)(diag >> 32), b);
      u64 mc = ((u64)dhi << 32) | (u64)dlo;    // scalar: row b's within-chunk suppression
      u64 bit = (cur >> b) & 1ull;             // scalar chain: ~4 SALU/iter
      u64 bm = 0ull - bit;
      cur &= ~(mc & bm);
      kept |= bit << b;
    }
    // per-lane rem update for future chunks: my half's 32 rows, my word
    unsigned kh = half ? (unsigned)(kept >> 32) : (unsigned)(kept & 0xFFFFFFFFull);
    #pragma unroll
    for (int b = 0; b < 32; ++b) {
      unsigned kb = (kh >> b) & 1u;
      u64 km = 0ull - (u64)kb;
      rem |= mw[b] & km;
    }
    rem |= __shfl(rem, lane ^ 32);   // merge halves
  }
  u64 kfin = k0 & ~rem;   // lanes >=32 hold 0 (k0=0 there)
  // fused output write: boxes_out (2000x4) then keep (2000)
  #pragma unroll
  for (int base = 0; base < M_TOP; base += 64) {
    int w = base >> 6;   // uniform
    unsigned wlo = (unsigned)__builtin_amdgcn_readlane((int)(unsigned)(kfin & 0xFFFFFFFFull), w);
    unsigned whi = (unsigned)__builtin_amdgcn_readlane((int)(unsigned)(kfin >> 32), w);
    u64 wbits = ((u64)whi << 32) | (u64)wlo;
    int i = base + lane;
    if (i < M_TOP) {
      int kb = (int)((wbits >> lane) & 1ull);
      float4 b = boxes[i];
      float4 o = kb ? b : make_float4(0.f, 0.f, 0.f, 0.f);
      ((float4*)out)[i] = o;
      out[4 * M_TOP + i] = kb ? 1.0f : 0.0f;
    }
  }
}

extern "C" void kernel_launch(void* const* d_in, const int* in_sizes, int n_in,
                              void* d_out, int out_size, void* d_ws, size_t ws_size,
                              hipStream_t stream) {
  const float* anchors = (const float*)d_in[0];
  const float* score   = (const float*)d_in[1];
  const float* boxreg  = (const float*)d_in[2];
  float* out = (float*)d_out;
  char* ws = (char*)d_ws;

  unsigned int* hist   = (unsigned int*)(ws + OFF_HIST);
  unsigned int* meta   = (unsigned int*)(ws + OFF_META);
  u64*          keys   = (u64*)(ws + OFF_KEYS);
  u64*          sorted = (u64*)(ws + OFF_SORTED);
  float4*       boxes  = (float4*)(ws + OFF_BOXES);
  unsigned int* flags  = (unsigned int*)(ws + OFF_FLAGS);
  u64*          mask   = (u64*)(ws + OFF_MASK);

  hipMemsetAsync(ws, 0, ZERO_BYTES, stream);
  hist_kernel<<<1024, 256, 0, stream>>>((const float4*)score, hist);
  thresh_kernel<<<1, 64, 0, stream>>>(hist, meta);
  compact_kernel<<<1024, 256, 0, stream>>>((const float4*)score, meta, keys);
  rank_kernel<<<CAP / 256, 256, 0, stream>>>(keys, meta, sorted);
  decode_kernel<<<8, 256, 0, stream>>>(sorted, (const float4*)anchors,
                                       (const float4*)boxreg, boxes, flags);
  mask_kernel<<<M_TOP, 256, 0, stream>>>(boxes, mask);
  reduce_kernel<<<1, 64, 0, stream>>>(mask, flags, boxes, out);
}